// Round 5
// baseline (374.438 us; speedup 1.0000x reference)
//
#include <hip/hip_runtime.h>
#include <cstdint>
#include <cstddef>

// ---------------------------------------------------------------------------
// MultiHeadAttention (B=32,N=577,D=768,H=12,Hd=64), anti-causal mask quirk,
// scale 1/sqrt(768). bf16 MFMA pipeline:
//   cast -> fused QKV GEMM (BK=64, LDS-coalesced Q/K/Vb stores) ->
//   Vb->Vt transpose (zero-filled n>=577) -> flash attention (q128, swapped
//   QK^T, Q direct-to-reg, b64 P-stores, hoisted V frags, no-max exp2
//   softmax, MFMA row-sums, setprio on MFMA clusters) -> out GEMM (BK=64)
// R10 = R8 frozen (5th straight GPU-acquisition timeout). Holding the stack
// unchanged: with zero landed measurements on R6-R8, further blind edits are
// negative-EV; priority is one clean, attributable bench. Audit #4 passed
// (uninitialized-memory paths: all garbage reads masked-to-zero or
// store-guarded before any NaN-minting arithmetic).
// ---------------------------------------------------------------------------

typedef __bf16 bf16;
typedef __bf16 bf16x4 __attribute__((ext_vector_type(4)));
typedef __bf16 bf16x8 __attribute__((ext_vector_type(8)));
typedef float  f32x4  __attribute__((ext_vector_type(4)));

#define DEVI __device__ __forceinline__

constexpr int BATCH = 32;
constexpr int NSEQ  = 577;
constexpr int DMODEL= 768;
constexpr int NHEAD = 12;
constexpr int HD    = 64;
constexpr int M_ROWS = BATCH * NSEQ;        // 18464
constexpr int M_PAD  = 145 * 128;           // 18560
constexpr int N_PAD  = 640;                 // seq padded to 10*64
constexpr int QKV_N  = 3 * DMODEL;          // 2304
// Q pre-scaled by (1/sqrt(768)) * log2(e) so attention uses exp2 directly.
constexpr float QSCALE = 0.036084391824351615f * 1.4426950408889634f;

DEVI void async_copy16(const void* g, void* l) {
  void* gg = (void*)(uintptr_t)g;
  __builtin_amdgcn_global_load_lds(
      (__attribute__((address_space(1))) void*)gg,
      (__attribute__((address_space(3))) void*)l,
      16, 0, 0);
}

DEVI f32x4 mfma16(bf16x8 a, bf16x8 b, f32x4 c) {
  return __builtin_amdgcn_mfma_f32_16x16x32_bf16(a, b, c, 0, 0, 0);
}

// ---------------------------------------------------------------------------
// Kernel 1: cast x and weights to bf16. wcat = [Wq;Wk;Wv] rows, wob = Wo.
// ---------------------------------------------------------------------------
__global__ __launch_bounds__(256) void cast_kernel(
    const float* __restrict__ x,
    const float* __restrict__ wq, const float* __restrict__ wk,
    const float* __restrict__ wv, const float* __restrict__ wo,
    bf16* __restrict__ xb, bf16* __restrict__ wcat, bf16* __restrict__ wob)
{
  constexpr int XQ = (M_ROWS * DMODEL) / 4;
  constexpr int WQ = (DMODEL * DMODEL) / 4;
  int idx = blockIdx.x * 256 + threadIdx.x;
  const float4* src; bf16* dst; int off;
  if (idx < XQ) { src = (const float4*)x; dst = xb; off = idx; }
  else {
    int u = idx - XQ; int w = u / WQ; off = u - w * WQ;
    src = (const float4*)(w == 0 ? wq : w == 1 ? wk : w == 2 ? wv : wo);
    dst = (w < 3) ? (wcat + (size_t)w * DMODEL * DMODEL) : wob;
  }
  float4 v = src[off];
  bf16x4 o;
  o[0] = (bf16)v.x; o[1] = (bf16)v.y; o[2] = (bf16)v.z; o[3] = (bf16)v.w;
  *(bf16x4*)(dst + (size_t)off * 4) = o;
}

// ---------------------------------------------------------------------------
// GEMM C = A[M x 768] * Bw[Nt x 768]^T (+bias). 128x128 tile, BK=64,
// global_load_lds x16. LDS rows are 64 bf16 (128 B); slot (row, lin) holds
// global chunk lin ^ (row&7)  [8 chunks of 16B per row]. Frag read uses the
// same key -> uniform bank load (same scheme as attn staging).
// MODE 0: Nt=2304, LDS-staged epilogue -> coalesced bf16x8 Q/K/Vb stores.
// MODE 1: Nt=768, store fp32 to Cout (guard m<18464), bias0 = bo
// ---------------------------------------------------------------------------
template <int MODE>
__global__ __launch_bounds__(256) void gemm_bt(
    const bf16* __restrict__ A, const bf16* __restrict__ Bw,
    const float* __restrict__ bias0, const float* __restrict__ bias1,
    const float* __restrict__ bias2,
    float* __restrict__ Cout,
    bf16* __restrict__ Qb, bf16* __restrict__ Kb, bf16* __restrict__ Vb)
{
  // 32 KB: K-loop As/Bs (16 KB each); MODE 0 epilogue reuses as 128x72 C-stage.
  __shared__ __align__(16) char smem[32768];
  bf16* As = (bf16*)smem;                     // 128 x 64 bf16
  bf16* Bs = (bf16*)(smem + 16384);           // 128 x 64 bf16
  const int t = threadIdx.x;
  const int w = t >> 6, lane = t & 63;
  const int g = lane >> 4, cl = lane & 15;
  const int wm = (w >> 1) * 64, wn = (w & 1) * 64;
  const int m0 = blockIdx.y * 128, n0 = blockIdx.x * 128;

  f32x4 acc[4][4] = {};

  const int srow = t >> 3;                        // 0..31
  const int scol = ((t & 7) ^ (srow & 7)) * 8;    // swizzled source chunk
  const bf16* Ag = A  + (size_t)(m0 + srow) * 768 + scol;
  const bf16* Bg = Bw + (size_t)(n0 + srow) * 768 + scol;
  char* lA = smem + w * 1024;
  char* lB = smem + 16384 + w * 1024;

  for (int kb = 0; kb < 768; kb += 64) {
#pragma unroll
    for (int c = 0; c < 4; ++c) {
      async_copy16(Ag + kb + (size_t)c * 32 * 768, lA + c * 4096);
      async_copy16(Bg + kb + (size_t)c * 32 * 768, lB + c * 4096);
    }
    __syncthreads();
#pragma unroll
    for (int ks = 0; ks < 2; ++ks) {
      const int ch = ((ks * 4 + g) ^ (cl & 7)) * 8;
      bf16x8 af[4], bfr[4];
#pragma unroll
      for (int i = 0; i < 4; ++i)
        af[i] = *(const bf16x8*)(As + (wm + i * 16 + cl) * 64 + ch);
#pragma unroll
      for (int j = 0; j < 4; ++j)
        bfr[j] = *(const bf16x8*)(Bs + (wn + j * 16 + cl) * 64 + ch);
#pragma unroll
      for (int i = 0; i < 4; ++i)
#pragma unroll
        for (int j = 0; j < 4; ++j)
          acc[i][j] = mfma16(af[i], bfr[j], acc[i][j]);
    }
    __syncthreads();
  }

  // Epilogue. C/D layout: row = g*4 + r, col = cl (per 16x16 frag).
  if constexpr (MODE == 0) {
    bf16* Cs = (bf16*)smem;                   // 128 x 72 stride
    // Two passes over the 64-col halves; waves with wn==p*64 own pass p.
#pragma unroll
    for (int p = 0; p < 2; ++p) {
      __syncthreads();                        // LDS free (K-loop / prev pass)
      if ((w & 1) == p) {
#pragma unroll
        for (int j = 0; j < 4; ++j) {
          const int n = n0 + wn + j * 16 + cl;            // 0..2303
          const int which = n >= 1536 ? 2 : (n >= 768 ? 1 : 0);
          const int rem = n - which * 768;
          const float bias =
              (which == 0 ? bias0 : which == 1 ? bias1 : bias2)[rem];
          const float sc = which == 0 ? QSCALE : 1.0f;
#pragma unroll
          for (int i = 0; i < 4; ++i)
#pragma unroll
            for (int r = 0; r < 4; ++r)
              Cs[(wm + i * 16 + g * 4 + r) * 72 + j * 16 + cl] =
                  (bf16)((acc[i][j][r] + bias) * sc);
        }
      }
      __syncthreads();
      // read & store: thread t owns row t>>1, cols (t&1)*32 .. +31
      const int nbase = n0 + p * 64;
      const int which = nbase >= 1536 ? 2 : (nbase >= 768 ? 1 : 0);
      const int rem0 = nbase - which * 768;
      const int h = rem0 >> 6;
      bf16* dst = which == 0 ? Qb : which == 1 ? Kb : Vb;
      const int row = t >> 1, colh = (t & 1) * 32;
      const unsigned m = (unsigned)(m0 + row);
      if (m < (unsigned)M_ROWS) {
        const unsigned bb = m / 577u;
        const unsigned nq = m - bb * 577u;
        bf16* dr = dst + ((size_t)(bb * NHEAD + h) * N_PAD + nq) * HD + colh;
        const bf16* sr = Cs + row * 72 + colh;
#pragma unroll
        for (int cc = 0; cc < 4; ++cc)
          *(bf16x8*)(dr + cc * 8) = *(const bf16x8*)(sr + cc * 8);
      }
    }
  } else {
#pragma unroll
    for (int j = 0; j < 4; ++j) {
      const int n = n0 + wn + j * 16 + cl;              // 0..767
      const float bias = bias0[n];
#pragma unroll
      for (int i = 0; i < 4; ++i) {
#pragma unroll
        for (int r = 0; r < 4; ++r) {
          const unsigned m = (unsigned)(m0 + wm + i * 16 + g * 4 + r);
          if (m < (unsigned)M_ROWS)
            Cout[(size_t)m * 768 + n] = acc[i][j][r] + bias;
        }
      }
    }
  }
}

// ---------------------------------------------------------------------------
// Kernel 2b: Vb [bh][n=640][d=64] -> Vt [bh][d=64][n=640], 64x64 LDS tiles.
// Padding rows n >= 577 are written as ZERO (Vb rows there are never written
// by the QKV GEMM; 0*garbage in PV would risk NaN under poisoned workspace).
// ---------------------------------------------------------------------------
__global__ __launch_bounds__(256) void transpose_v(
    const bf16* __restrict__ Vb, bf16* __restrict__ Vt)
{
  __shared__ __align__(16) bf16 Ls[64 * 72];    // pad 72 to spread banks
  const int t = threadIdx.x;
  const int bh = blockIdx.y, n0 = blockIdx.x * 64;

  const int nrow = n0 + (t >> 3);
  const bf16* src = Vb + ((size_t)bh * N_PAD + nrow) * HD + (t & 7) * 8;
  const bf16x8 z = {};
  bf16x8 a0 = (nrow      < NSEQ) ? *(const bf16x8*)src                      : z;
  bf16x8 a1 = (nrow + 32 < NSEQ) ? *(const bf16x8*)(src + (size_t)32 * HD)  : z;
  *(bf16x8*)(Ls + (t >> 3) * 72 + (t & 7) * 8) = a0;
  *(bf16x8*)(Ls + ((t >> 3) + 32) * 72 + (t & 7) * 8) = a1;
  __syncthreads();

  const int d = t >> 2, nc = (t & 3) * 16;
  bf16 o[16];
#pragma unroll
  for (int e = 0; e < 16; ++e) o[e] = Ls[(nc + e) * 72 + d];
  bf16* dst = Vt + ((size_t)bh * HD + d) * N_PAD + n0 + nc;
  *(bf16x8*)dst = *(bf16x8*)o;
  *(bf16x8*)(dst + 8) = *(bf16x8*)(o + 8);
}

// ---------------------------------------------------------------------------
// Kernel 3: flash attention, anti-causal (k >= q allowed). Q pre-scaled ->
// p = exp2(s), no running max (|s| <~ 3; normalization cancels).
// QK^T computed SWAPPED: s = mfma(K, Q) so fragment row = k, col = q.
// -> each lane holds 4 consecutive k at fixed q -> P store = 8x ds_write_b64.
// Q loaded straight to registers (no LDS). V/P fragments hoisted so each is
// read exactly once. Row sums via ones-column MFMA. 128 q rows/block, K/V
// double-buffered. LDS 48 KB -> 3 blocks/CU. setprio(1) on MFMA clusters.
// ---------------------------------------------------------------------------
__global__ __launch_bounds__(256) void attn_kernel(
    const bf16* __restrict__ Qb, const bf16* __restrict__ Kb,
    const bf16* __restrict__ Vtb, bf16* __restrict__ Ao)
{
  __shared__ __align__(16) bf16 Ks[2][64 * 64];         // 16 KB
  __shared__ __align__(16) bf16 Vs[2][64 * 64];         // 16 KB
  __shared__ __align__(16) bf16 Ps[4 * 32 * 64];        // 16 KB, per-wave [32][64]

  const int t = threadIdx.x, w = t >> 6, lane = t & 63;
  const int g = lane >> 4, cl = lane & 15;
  const int qt = blockIdx.x;            // 0..4 (128 q rows each)
  const int bh = blockIdx.y;            // b*12+h
  const size_t kqbase = (size_t)bh * (N_PAD * HD);
  const size_t vbase  = (size_t)bh * (HD * N_PAD);

  const int srow = t >> 3;                       // 0..31
  const int scol = ((t & 7) ^ (srow & 7)) * 8;   // swizzled source chunk

  const bf16* Kg = Kb  + kqbase + (size_t)srow * HD + scol;
  const bf16* Vg = Vtb + vbase  + (size_t)srow * N_PAD + scol;

  const int jb0 = 2 * qt, nit = 10 - jb0;

  // Q direct to registers (issued before the barrier so it overlaps staging).
  bf16x8 aq[2][2];                      // [f][ks]
#pragma unroll
  for (int ks = 0; ks < 2; ++ks)
#pragma unroll
    for (int f = 0; f < 2; ++f)
      aq[f][ks] = *(const bf16x8*)(
          Qb + kqbase + (size_t)(qt * 128 + w * 32 + f * 16 + cl) * HD +
          (ks * 4 + g) * 8);

#pragma unroll
  for (int c = 0; c < 2; ++c) {
    async_copy16(Kg + (size_t)(jb0 * 64 + c * 32) * HD,  (char*)Ks[0] + c * 4096 + w * 1024);
    async_copy16(Vg + jb0 * 64 + (size_t)(c * 32) * N_PAD, (char*)Vs[0] + c * 4096 + w * 1024);
  }
  __syncthreads();

  f32x4 oacc[2][4] = {};
  f32x4 lsum[2] = {};
  bf16x8 onesf;
#pragma unroll
  for (int e = 0; e < 8; ++e) onesf[e] = (bf16)(cl == 0 ? 1.0f : 0.0f);

  bf16* pw = Ps + w * 2048;             // per-wave P tile [32][64]
  const int qw0 = qt * 128 + w * 32;    // wave's first q row

  for (int it = 0; it < nit; ++it) {
    const int jb = jb0 + it;
    const int buf = it & 1;
    if (it + 1 < nit) {
      const int jn = jb + 1, nb = buf ^ 1;
#pragma unroll
      for (int c = 0; c < 2; ++c) {
        async_copy16(Kg + (size_t)(jn * 64 + c * 32) * HD,   (char*)Ks[nb] + c * 4096 + w * 1024);
        async_copy16(Vg + jn * 64 + (size_t)(c * 32) * N_PAD, (char*)Vs[nb] + c * 4096 + w * 1024);
      }
    }

    // Swapped QK^T: s[f][j] fragment holds S^T: row = k = j*16+g*4+r,
    // col = q = f*16+cl.
    f32x4 s[2][4] = {};
    __builtin_amdgcn_s_setprio(1);
#pragma unroll
    for (int ks = 0; ks < 2; ++ks) {
      const int chk = ((ks * 4 + g) ^ (cl & 7)) * 8;
#pragma unroll
      for (int j = 0; j < 4; ++j) {
        bf16x8 bk = *(const bf16x8*)(Ks[buf] + (j * 16 + cl) * 64 + chk);
#pragma unroll
        for (int f = 0; f < 2; ++f)
          s[f][j] = mfma16(bk, aq[f][ks], s[f][j]);
      }
    }
    __builtin_amdgcn_s_setprio(0);

    float p[2][4][4];
    const bool need_mask = (jb * 64 < qw0 + 32) || (jb == 9);
    if (need_mask) {
#pragma unroll
      for (int f = 0; f < 2; ++f) {
        const int qglob = qw0 + f * 16 + cl;
#pragma unroll
        for (int j = 0; j < 4; ++j) {
#pragma unroll
          for (int r = 0; r < 4; ++r) {
            const int kg = jb * 64 + j * 16 + g * 4 + r;
            const bool ok = (kg >= qglob) && (kg < NSEQ);
            p[f][j][r] = ok ? exp2f(s[f][j][r]) : 0.f;
          }
        }
      }
    } else {
#pragma unroll
      for (int f = 0; f < 2; ++f)
#pragma unroll
        for (int j = 0; j < 4; ++j)
#pragma unroll
          for (int r = 0; r < 4; ++r)
            p[f][j][r] = exp2f(s[f][j][r]);
    }

    // P store: per (f,j) the 4 r-values are 4 consecutive k at fixed q-row
    // -> one 8-byte write. Chunk c = j*2 + (g>>1), half = g&1; swizzle key
    // (row&7)=(cl&7) matches the PV/lsum read path exactly.
#pragma unroll
    for (int f = 0; f < 2; ++f) {
      const int prow = f * 16 + cl;
      bf16* pr = pw + prow * 64;
      const int rk = prow & 7;
#pragma unroll
      for (int j = 0; j < 4; ++j) {
        const int c = j * 2 + (g >> 1);
        bf16x4 tmp;
#pragma unroll
        for (int r = 0; r < 4; ++r) tmp[r] = (bf16)p[f][j][r];
        *(bf16x4*)(pr + ((c ^ rk) * 8) + (g & 1) * 4) = tmp;
      }
    }

    // PV + row sums. Each ap/bv fragment read exactly once.
#pragma unroll
    for (int ks = 0; ks < 2; ++ks) {
      const int chp = ((ks * 4 + g) ^ (cl & 7)) * 8;
      bf16x8 ap[2], bv[4];
#pragma unroll
      for (int f = 0; f < 2; ++f)
        ap[f] = *(const bf16x8*)(pw + (f * 16 + cl) * 64 + chp);
#pragma unroll
      for (int j = 0; j < 4; ++j)
        bv[j] = *(const bf16x8*)(Vs[buf] + (j * 16 + cl) * 64 + chp);
      __builtin_amdgcn_s_setprio(1);
#pragma unroll
      for (int f = 0; f < 2; ++f) {
#pragma unroll
        for (int j = 0; j < 4; ++j)
          oacc[f][j] = mfma16(ap[f], bv[j], oacc[f][j]);
        lsum[f] = mfma16(ap[f], onesf, lsum[f]);
      }
      __builtin_amdgcn_s_setprio(0);
    }
    __syncthreads();
  }

  const int b_ = bh / NHEAD, h_ = bh - (bh / NHEAD) * NHEAD;
#pragma unroll
  for (int f = 0; f < 2; ++f)
#pragma unroll
    for (int r = 0; r < 4; ++r) {
      const int qg = qw0 + f * 16 + g * 4 + r;
      const float l = __shfl(lsum[f][r], lane & 48, 64);
      if (qg >= NSEQ) continue;
      const float inv = 1.f / l;
      const size_t row = ((size_t)b_ * NSEQ + qg) * DMODEL + h_ * HD;
#pragma unroll
      for (int j = 0; j < 4; ++j)
        Ao[row + j * 16 + cl] = (bf16)(oacc[f][j][r] * inv);
    }
}

// ---------------------------------------------------------------------------
extern "C" void kernel_launch(void* const* d_in, const int* in_sizes, int n_in,
                              void* d_out, int out_size, void* d_ws, size_t ws_size,
                              hipStream_t stream) {
  const float* x  = (const float*)d_in[0];
  const float* Wq = (const float*)d_in[1];
  const float* bq = (const float*)d_in[2];
  const float* Wk = (const float*)d_in[3];
  const float* bk = (const float*)d_in[4];
  const float* Wv = (const float*)d_in[5];
  const float* bv = (const float*)d_in[6];
  const float* Wo = (const float*)d_in[7];
  const float* bo = (const float*)d_in[8];

  char* ws = (char*)d_ws;
  size_t off = 0;
  auto alloc = [&](size_t bytes) -> char* {
    char* p = ws + off;
    off += (bytes + 255) & ~(size_t)255;
    return p;
  };
  bf16* xb   = (bf16*)alloc((size_t)M_PAD * DMODEL * 2);
  bf16* wcat = (bf16*)alloc((size_t)QKV_N * DMODEL * 2);
  bf16* wob  = (bf16*)alloc((size_t)DMODEL * DMODEL * 2);
  bf16* Qb   = (bf16*)alloc((size_t)BATCH * NHEAD * N_PAD * HD * 2);
  bf16* Kb   = (bf16*)alloc((size_t)BATCH * NHEAD * N_PAD * HD * 2);
  bf16* Vb   = (bf16*)alloc((size_t)BATCH * NHEAD * N_PAD * HD * 2);
  bf16* Vtb  = (bf16*)alloc((size_t)BATCH * NHEAD * HD * N_PAD * 2);
  bf16* Ao   = (bf16*)alloc((size_t)M_PAD * DMODEL * 2);
  (void)ws_size; (void)in_sizes; (void)n_in; (void)out_size;

  constexpr int XQ = (M_ROWS * DMODEL) / 4;
  constexpr int WQ = (DMODEL * DMODEL) / 4;
  const int cast_blocks = (XQ + 4 * WQ) / 256;
  cast_kernel<<<cast_blocks, 256, 0, stream>>>(x, Wq, Wk, Wv, Wo, xb, wcat, wob);

  gemm_bt<0><<<dim3(QKV_N / 128, M_PAD / 128), 256, 0, stream>>>(
      xb, wcat, bq, bk, bv, nullptr, Qb, Kb, Vb);

  transpose_v<<<dim3(N_PAD / 64, BATCH * NHEAD), 256, 0, stream>>>(Vb, Vtb);

  attn_kernel<<<dim3(5, BATCH * NHEAD), 256, 0, stream>>>(Qb, Kb, Vtb, Ao);

  gemm_bt<1><<<dim3(DMODEL / 128, M_PAD / 128), 256, 0, stream>>>(
      Ao, wob, bo, nullptr, nullptr, (float*)d_out, nullptr, nullptr, nullptr);
}

// Round 6
// 340.495 us; speedup vs baseline: 1.0997x; 1.0997x over previous
//
#include <hip/hip_runtime.h>
#include <cstdint>
#include <cstddef>

// ---------------------------------------------------------------------------
// MultiHeadAttention (B=32,N=577,D=768,H=12,Hd=64), anti-causal mask quirk,
// scale 1/sqrt(768). bf16 MFMA pipeline:
//   cast -> fused QKV GEMM -> Vb->Vt transpose (zero-filled n>=577) ->
//   flash attention (q128, swapped QK^T, Q direct-to-reg, b64 P-stores,
//   no-max exp2 softmax, MFMA row-sums, setprio) -> out GEMM
// R11 changes vs R10 (first landed bench: 374.4us, passed; gemm_bt<0>
// counters: MfmaUtil 22.7%, HBM 25%, Occupancy 18.9% -> barrier/latency
// bound, stage and compute fully serialized):
//   * gemm_bt K-loop: double-buffered LDS (64 KB), stage(t+1) issued BEFORE
//     compute(t), ONE barrier per K-step (same proven pattern as attn).
//     Barrier vmcnt(0) now waits on loads issued ~350cy earlier, not 0cy.
//   * gemm_bt: bijective XCD-chunked blockIdx swizzle (m204) -> consecutive
//     tiles (sharing A-panels) land on the same XCD L2; FETCH_SIZE 152MB
//     was ~5x ideal.
//   * attn/cast/transpose byte-identical to R10 (verified).
// ---------------------------------------------------------------------------

typedef __bf16 bf16;
typedef __bf16 bf16x4 __attribute__((ext_vector_type(4)));
typedef __bf16 bf16x8 __attribute__((ext_vector_type(8)));
typedef float  f32x4  __attribute__((ext_vector_type(4)));

#define DEVI __device__ __forceinline__

constexpr int BATCH = 32;
constexpr int NSEQ  = 577;
constexpr int DMODEL= 768;
constexpr int NHEAD = 12;
constexpr int HD    = 64;
constexpr int M_ROWS = BATCH * NSEQ;        // 18464
constexpr int M_PAD  = 145 * 128;           // 18560
constexpr int N_PAD  = 640;                 // seq padded to 10*64
constexpr int QKV_N  = 3 * DMODEL;          // 2304
// Q pre-scaled by (1/sqrt(768)) * log2(e) so attention uses exp2 directly.
constexpr float QSCALE = 0.036084391824351615f * 1.4426950408889634f;

DEVI void async_copy16(const void* g, void* l) {
  void* gg = (void*)(uintptr_t)g;
  __builtin_amdgcn_global_load_lds(
      (__attribute__((address_space(1))) void*)gg,
      (__attribute__((address_space(3))) void*)l,
      16, 0, 0);
}

DEVI f32x4 mfma16(bf16x8 a, bf16x8 b, f32x4 c) {
  return __builtin_amdgcn_mfma_f32_16x16x32_bf16(a, b, c, 0, 0, 0);
}

// ---------------------------------------------------------------------------
// Kernel 1: cast x and weights to bf16. wcat = [Wq;Wk;Wv] rows, wob = Wo.
// ---------------------------------------------------------------------------
__global__ __launch_bounds__(256) void cast_kernel(
    const float* __restrict__ x,
    const float* __restrict__ wq, const float* __restrict__ wk,
    const float* __restrict__ wv, const float* __restrict__ wo,
    bf16* __restrict__ xb, bf16* __restrict__ wcat, bf16* __restrict__ wob)
{
  constexpr int XQ = (M_ROWS * DMODEL) / 4;
  constexpr int WQ = (DMODEL * DMODEL) / 4;
  int idx = blockIdx.x * 256 + threadIdx.x;
  const float4* src; bf16* dst; int off;
  if (idx < XQ) { src = (const float4*)x; dst = xb; off = idx; }
  else {
    int u = idx - XQ; int w = u / WQ; off = u - w * WQ;
    src = (const float4*)(w == 0 ? wq : w == 1 ? wk : w == 2 ? wv : wo);
    dst = (w < 3) ? (wcat + (size_t)w * DMODEL * DMODEL) : wob;
  }
  float4 v = src[off];
  bf16x4 o;
  o[0] = (bf16)v.x; o[1] = (bf16)v.y; o[2] = (bf16)v.z; o[3] = (bf16)v.w;
  *(bf16x4*)(dst + (size_t)off * 4) = o;
}

// ---------------------------------------------------------------------------
// GEMM C = A[M x 768] * Bw[Nt x 768]^T (+bias). 128x128 tile, BK=64,
// DOUBLE-BUFFERED: stage(t+1) via global_load_lds issued before compute(t),
// one __syncthreads per K-step (its vmcnt(0) drains loads issued a full
// compute-phase earlier). LDS rows 64 bf16 (128 B), chunk swizzle
// lin ^ (row&7); frag read uses the same key -> uniform bank load.
// Bijective XCD-chunked tile swizzle (m204): consecutive tiles -> same XCD.
// MODE 0: Nt=2304, LDS-staged epilogue -> coalesced bf16x8 Q/K/Vb stores.
// MODE 1: Nt=768, store fp32 to Cout (guard m<18464), bias0 = bo
// ---------------------------------------------------------------------------
template <int MODE>
__global__ __launch_bounds__(256) void gemm_bt(
    const bf16* __restrict__ A, const bf16* __restrict__ Bw,
    const float* __restrict__ bias0, const float* __restrict__ bias1,
    const float* __restrict__ bias2,
    float* __restrict__ Cout,
    bf16* __restrict__ Qb, bf16* __restrict__ Kb, bf16* __restrict__ Vb)
{
  // 64 KB: dbuf K-loop {A,B} x {buf0,buf1}, 16 KB each.
  // MODE 0 epilogue reuses the first 18 KB as a 128x72 bf16 C-stage.
  __shared__ __align__(16) char smem[65536];
  const int t = threadIdx.x;
  const int w = t >> 6, lane = t & 63;
  const int g = lane >> 4, cl = lane & 15;
  const int wm = (w >> 1) * 64, wn = (w & 1) * 64;

  // --- bijective XCD-chunked swizzle (dispatch order l = y*GX + x) ---
  constexpr int GX  = (MODE == 0 ? QKV_N : DMODEL) / 128;   // 18 or 6
  constexpr int NWG = GX * (M_PAD / 128);                   // 2610 or 870
  constexpr int QC  = NWG / 8, RC = NWG % 8;
  const int l   = blockIdx.y * GX + blockIdx.x;
  const int xcd = l & 7, pos = l >> 3;
  const int nl  = (xcd < RC ? xcd * (QC + 1) : RC * (QC + 1) + (xcd - RC) * QC) + pos;
  const int m0  = (nl / GX) * 128, n0 = (nl % GX) * 128;

  f32x4 acc[4][4] = {};

  const int srow = t >> 3;                        // 0..31
  const int scol = ((t & 7) ^ (srow & 7)) * 8;    // swizzled source chunk
  const bf16* Ag = A  + (size_t)(m0 + srow) * 768 + scol;
  const bf16* Bg = Bw + (size_t)(n0 + srow) * 768 + scol;

  constexpr int NSTEP = 768 / 64;                 // 12
  auto stage = [&](int st, int buf) {
    char* lA = smem + buf * 32768 + w * 1024;
    char* lB = smem + buf * 32768 + 16384 + w * 1024;
#pragma unroll
    for (int c = 0; c < 4; ++c) {
      async_copy16(Ag + st * 64 + (size_t)c * 32 * 768, lA + c * 4096);
      async_copy16(Bg + st * 64 + (size_t)c * 32 * 768, lB + c * 4096);
    }
  };

  stage(0, 0);
  __syncthreads();                                // buf0 ready

  for (int st = 0; st < NSTEP; ++st) {
    const int cur = st & 1;
    if (st + 1 < NSTEP) stage(st + 1, cur ^ 1);   // prefetch overlaps compute
    const bf16* As = (const bf16*)(smem + cur * 32768);
    const bf16* Bs = (const bf16*)(smem + cur * 32768 + 16384);
#pragma unroll
    for (int ks = 0; ks < 2; ++ks) {
      const int ch = ((ks * 4 + g) ^ (cl & 7)) * 8;
      bf16x8 af[4], bfr[4];
#pragma unroll
      for (int i = 0; i < 4; ++i)
        af[i] = *(const bf16x8*)(As + (wm + i * 16 + cl) * 64 + ch);
#pragma unroll
      for (int j = 0; j < 4; ++j)
        bfr[j] = *(const bf16x8*)(Bs + (wn + j * 16 + cl) * 64 + ch);
#pragma unroll
      for (int i = 0; i < 4; ++i)
#pragma unroll
        for (int j = 0; j < 4; ++j)
          acc[i][j] = mfma16(af[i], bfr[j], acc[i][j]);
    }
    __syncthreads();   // drains vmcnt(0): next-tile stage done; reads done
  }

  // Epilogue. C/D layout: row = g*4 + r, col = cl (per 16x16 frag).
  if constexpr (MODE == 0) {
    bf16* Cs = (bf16*)smem;                   // 128 x 72 stride
    // Two passes over the 64-col halves; waves with wn==p*64 own pass p.
#pragma unroll
    for (int p = 0; p < 2; ++p) {
      __syncthreads();                        // LDS free (K-loop / prev pass)
      if ((w & 1) == p) {
#pragma unroll
        for (int j = 0; j < 4; ++j) {
          const int n = n0 + wn + j * 16 + cl;            // 0..2303
          const int which = n >= 1536 ? 2 : (n >= 768 ? 1 : 0);
          const int rem = n - which * 768;
          const float bias =
              (which == 0 ? bias0 : which == 1 ? bias1 : bias2)[rem];
          const float sc = which == 0 ? QSCALE : 1.0f;
#pragma unroll
          for (int i = 0; i < 4; ++i)
#pragma unroll
            for (int r = 0; r < 4; ++r)
              Cs[(wm + i * 16 + g * 4 + r) * 72 + j * 16 + cl] =
                  (bf16)((acc[i][j][r] + bias) * sc);
        }
      }
      __syncthreads();
      // read & store: thread t owns row t>>1, cols (t&1)*32 .. +31
      const int nbase = n0 + p * 64;
      const int which = nbase >= 1536 ? 2 : (nbase >= 768 ? 1 : 0);
      const int rem0 = nbase - which * 768;
      const int h = rem0 >> 6;
      bf16* dst = which == 0 ? Qb : which == 1 ? Kb : Vb;
      const int row = t >> 1, colh = (t & 1) * 32;
      const unsigned m = (unsigned)(m0 + row);
      if (m < (unsigned)M_ROWS) {
        const unsigned bb = m / 577u;
        const unsigned nq = m - bb * 577u;
        bf16* dr = dst + ((size_t)(bb * NHEAD + h) * N_PAD + nq) * HD + colh;
        const bf16* sr = Cs + row * 72 + colh;
#pragma unroll
        for (int cc = 0; cc < 4; ++cc)
          *(bf16x8*)(dr + cc * 8) = *(const bf16x8*)(sr + cc * 8);
      }
    }
  } else {
#pragma unroll
    for (int j = 0; j < 4; ++j) {
      const int n = n0 + wn + j * 16 + cl;              // 0..767
      const float bias = bias0[n];
#pragma unroll
      for (int i = 0; i < 4; ++i) {
#pragma unroll
        for (int r = 0; r < 4; ++r) {
          const unsigned m = (unsigned)(m0 + wm + i * 16 + g * 4 + r);
          if (m < (unsigned)M_ROWS)
            Cout[(size_t)m * 768 + n] = acc[i][j][r] + bias;
        }
      }
    }
  }
}

// ---------------------------------------------------------------------------
// Kernel 2b: Vb [bh][n=640][d=64] -> Vt [bh][d=64][n=640], 64x64 LDS tiles.
// Padding rows n >= 577 are written as ZERO (Vb rows there are never written
// by the QKV GEMM; 0*garbage in PV would risk NaN under poisoned workspace).
// ---------------------------------------------------------------------------
__global__ __launch_bounds__(256) void transpose_v(
    const bf16* __restrict__ Vb, bf16* __restrict__ Vt)
{
  __shared__ __align__(16) bf16 Ls[64 * 72];    // pad 72 to spread banks
  const int t = threadIdx.x;
  const int bh = blockIdx.y, n0 = blockIdx.x * 64;

  const int nrow = n0 + (t >> 3);
  const bf16* src = Vb + ((size_t)bh * N_PAD + nrow) * HD + (t & 7) * 8;
  const bf16x8 z = {};
  bf16x8 a0 = (nrow      < NSEQ) ? *(const bf16x8*)src                      : z;
  bf16x8 a1 = (nrow + 32 < NSEQ) ? *(const bf16x8*)(src + (size_t)32 * HD)  : z;
  *(bf16x8*)(Ls + (t >> 3) * 72 + (t & 7) * 8) = a0;
  *(bf16x8*)(Ls + ((t >> 3) + 32) * 72 + (t & 7) * 8) = a1;
  __syncthreads();

  const int d = t >> 2, nc = (t & 3) * 16;
  bf16 o[16];
#pragma unroll
  for (int e = 0; e < 16; ++e) o[e] = Ls[(nc + e) * 72 + d];
  bf16* dst = Vt + ((size_t)bh * HD + d) * N_PAD + n0 + nc;
  *(bf16x8*)dst = *(bf16x8*)o;
  *(bf16x8*)(dst + 8) = *(bf16x8*)(o + 8);
}

// ---------------------------------------------------------------------------
// Kernel 3: flash attention, anti-causal (k >= q allowed). Q pre-scaled ->
// p = exp2(s), no running max (|s| <~ 3; normalization cancels).
// QK^T computed SWAPPED: s = mfma(K, Q) so fragment row = k, col = q.
// -> each lane holds 4 consecutive k at fixed q -> P store = 8x ds_write_b64.
// Q loaded straight to registers (no LDS). V/P fragments hoisted so each is
// read exactly once. Row sums via ones-column MFMA. 128 q rows/block, K/V
// double-buffered. LDS 48 KB -> 3 blocks/CU. setprio(1) on MFMA clusters.
// ---------------------------------------------------------------------------
__global__ __launch_bounds__(256) void attn_kernel(
    const bf16* __restrict__ Qb, const bf16* __restrict__ Kb,
    const bf16* __restrict__ Vtb, bf16* __restrict__ Ao)
{
  __shared__ __align__(16) bf16 Ks[2][64 * 64];         // 16 KB
  __shared__ __align__(16) bf16 Vs[2][64 * 64];         // 16 KB
  __shared__ __align__(16) bf16 Ps[4 * 32 * 64];        // 16 KB, per-wave [32][64]

  const int t = threadIdx.x, w = t >> 6, lane = t & 63;
  const int g = lane >> 4, cl = lane & 15;
  const int qt = blockIdx.x;            // 0..4 (128 q rows each)
  const int bh = blockIdx.y;            // b*12+h
  const size_t kqbase = (size_t)bh * (N_PAD * HD);
  const size_t vbase  = (size_t)bh * (HD * N_PAD);

  const int srow = t >> 3;                       // 0..31
  const int scol = ((t & 7) ^ (srow & 7)) * 8;   // swizzled source chunk

  const bf16* Kg = Kb  + kqbase + (size_t)srow * HD + scol;
  const bf16* Vg = Vtb + vbase  + (size_t)srow * N_PAD + scol;

  const int jb0 = 2 * qt, nit = 10 - jb0;

  // Q direct to registers (issued before the barrier so it overlaps staging).
  bf16x8 aq[2][2];                      // [f][ks]
#pragma unroll
  for (int ks = 0; ks < 2; ++ks)
#pragma unroll
    for (int f = 0; f < 2; ++f)
      aq[f][ks] = *(const bf16x8*)(
          Qb + kqbase + (size_t)(qt * 128 + w * 32 + f * 16 + cl) * HD +
          (ks * 4 + g) * 8);

#pragma unroll
  for (int c = 0; c < 2; ++c) {
    async_copy16(Kg + (size_t)(jb0 * 64 + c * 32) * HD,  (char*)Ks[0] + c * 4096 + w * 1024);
    async_copy16(Vg + jb0 * 64 + (size_t)(c * 32) * N_PAD, (char*)Vs[0] + c * 4096 + w * 1024);
  }
  __syncthreads();

  f32x4 oacc[2][4] = {};
  f32x4 lsum[2] = {};
  bf16x8 onesf;
#pragma unroll
  for (int e = 0; e < 8; ++e) onesf[e] = (bf16)(cl == 0 ? 1.0f : 0.0f);

  bf16* pw = Ps + w * 2048;             // per-wave P tile [32][64]
  const int qw0 = qt * 128 + w * 32;    // wave's first q row

  for (int it = 0; it < nit; ++it) {
    const int jb = jb0 + it;
    const int buf = it & 1;
    if (it + 1 < nit) {
      const int jn = jb + 1, nb = buf ^ 1;
#pragma unroll
      for (int c = 0; c < 2; ++c) {
        async_copy16(Kg + (size_t)(jn * 64 + c * 32) * HD,   (char*)Ks[nb] + c * 4096 + w * 1024);
        async_copy16(Vg + jn * 64 + (size_t)(c * 32) * N_PAD, (char*)Vs[nb] + c * 4096 + w * 1024);
      }
    }

    // Swapped QK^T: s[f][j] fragment holds S^T: row = k = j*16+g*4+r,
    // col = q = f*16+cl.
    f32x4 s[2][4] = {};
    __builtin_amdgcn_s_setprio(1);
#pragma unroll
    for (int ks = 0; ks < 2; ++ks) {
      const int chk = ((ks * 4 + g) ^ (cl & 7)) * 8;
#pragma unroll
      for (int j = 0; j < 4; ++j) {
        bf16x8 bk = *(const bf16x8*)(Ks[buf] + (j * 16 + cl) * 64 + chk);
#pragma unroll
        for (int f = 0; f < 2; ++f)
          s[f][j] = mfma16(bk, aq[f][ks], s[f][j]);
      }
    }
    __builtin_amdgcn_s_setprio(0);

    float p[2][4][4];
    const bool need_mask = (jb * 64 < qw0 + 32) || (jb == 9);
    if (need_mask) {
#pragma unroll
      for (int f = 0; f < 2; ++f) {
        const int qglob = qw0 + f * 16 + cl;
#pragma unroll
        for (int j = 0; j < 4; ++j) {
#pragma unroll
          for (int r = 0; r < 4; ++r) {
            const int kg = jb * 64 + j * 16 + g * 4 + r;
            const bool ok = (kg >= qglob) && (kg < NSEQ);
            p[f][j][r] = ok ? exp2f(s[f][j][r]) : 0.f;
          }
        }
      }
    } else {
#pragma unroll
      for (int f = 0; f < 2; ++f)
#pragma unroll
        for (int j = 0; j < 4; ++j)
#pragma unroll
          for (int r = 0; r < 4; ++r)
            p[f][j][r] = exp2f(s[f][j][r]);
    }

    // P store: per (f,j) the 4 r-values are 4 consecutive k at fixed q-row
    // -> one 8-byte write. Chunk c = j*2 + (g>>1), half = g&1; swizzle key
    // (row&7)=(cl&7) matches the PV/lsum read path exactly.
#pragma unroll
    for (int f = 0; f < 2; ++f) {
      const int prow = f * 16 + cl;
      bf16* pr = pw + prow * 64;
      const int rk = prow & 7;
#pragma unroll
      for (int j = 0; j < 4; ++j) {
        const int c = j * 2 + (g >> 1);
        bf16x4 tmp;
#pragma unroll
        for (int r = 0; r < 4; ++r) tmp[r] = (bf16)p[f][j][r];
        *(bf16x4*)(pr + ((c ^ rk) * 8) + (g & 1) * 4) = tmp;
      }
    }

    // PV + row sums. Each ap/bv fragment read exactly once.
#pragma unroll
    for (int ks = 0; ks < 2; ++ks) {
      const int chp = ((ks * 4 + g) ^ (cl & 7)) * 8;
      bf16x8 ap[2], bv[4];
#pragma unroll
      for (int f = 0; f < 2; ++f)
        ap[f] = *(const bf16x8*)(pw + (f * 16 + cl) * 64 + chp);
#pragma unroll
      for (int j = 0; j < 4; ++j)
        bv[j] = *(const bf16x8*)(Vs[buf] + (j * 16 + cl) * 64 + chp);
      __builtin_amdgcn_s_setprio(1);
#pragma unroll
      for (int f = 0; f < 2; ++f) {
#pragma unroll
        for (int j = 0; j < 4; ++j)
          oacc[f][j] = mfma16(ap[f], bv[j], oacc[f][j]);
        lsum[f] = mfma16(ap[f], onesf, lsum[f]);
      }
      __builtin_amdgcn_s_setprio(0);
    }
    __syncthreads();
  }

  const int b_ = bh / NHEAD, h_ = bh - (bh / NHEAD) * NHEAD;
#pragma unroll
  for (int f = 0; f < 2; ++f)
#pragma unroll
    for (int r = 0; r < 4; ++r) {
      const int qg = qw0 + f * 16 + g * 4 + r;
      const float l = __shfl(lsum[f][r], lane & 48, 64);
      if (qg >= NSEQ) continue;
      const float inv = 1.f / l;
      const size_t row = ((size_t)b_ * NSEQ + qg) * DMODEL + h_ * HD;
#pragma unroll
      for (int j = 0; j < 4; ++j)
        Ao[row + j * 16 + cl] = (bf16)(oacc[f][j][r] * inv);
    }
}

// ---------------------------------------------------------------------------
extern "C" void kernel_launch(void* const* d_in, const int* in_sizes, int n_in,
                              void* d_out, int out_size, void* d_ws, size_t ws_size,
                              hipStream_t stream) {
  const float* x  = (const float*)d_in[0];
  const float* Wq = (const float*)d_in[1];
  const float* bq = (const float*)d_in[2];
  const float* Wk = (const float*)d_in[3];
  const float* bk = (const float*)d_in[4];
  const float* Wv = (const float*)d_in[5];
  const float* bv = (const float*)d_in[6];
  const float* Wo = (const float*)d_in[7];
  const float* bo = (const float*)d_in[8];

  char* ws = (char*)d_ws;
  size_t off = 0;
  auto alloc = [&](size_t bytes) -> char* {
    char* p = ws + off;
    off += (bytes + 255) & ~(size_t)255;
    return p;
  };
  bf16* xb   = (bf16*)alloc((size_t)M_PAD * DMODEL * 2);
  bf16* wcat = (bf16*)alloc((size_t)QKV_N * DMODEL * 2);
  bf16* wob  = (bf16*)alloc((size_t)DMODEL * DMODEL * 2);
  bf16* Qb   = (bf16*)alloc((size_t)BATCH * NHEAD * N_PAD * HD * 2);
  bf16* Kb   = (bf16*)alloc((size_t)BATCH * NHEAD * N_PAD * HD * 2);
  bf16* Vb   = (bf16*)alloc((size_t)BATCH * NHEAD * N_PAD * HD * 2);
  bf16* Vtb  = (bf16*)alloc((size_t)BATCH * NHEAD * HD * N_PAD * 2);
  bf16* Ao   = (bf16*)alloc((size_t)M_PAD * DMODEL * 2);
  (void)ws_size; (void)in_sizes; (void)n_in; (void)out_size;

  constexpr int XQ = (M_ROWS * DMODEL) / 4;
  constexpr int WQ = (DMODEL * DMODEL) / 4;
  const int cast_blocks = (XQ + 4 * WQ) / 256;
  cast_kernel<<<cast_blocks, 256, 0, stream>>>(x, Wq, Wk, Wv, Wo, xb, wcat, wob);

  gemm_bt<0><<<dim3(QKV_N / 128, M_PAD / 128), 256, 0, stream>>>(
      xb, wcat, bq, bk, bv, nullptr, Qb, Kb, Vb);

  transpose_v<<<dim3(N_PAD / 64, BATCH * NHEAD), 256, 0, stream>>>(Vb, Vtb);

  attn_kernel<<<dim3(5, BATCH * NHEAD), 256, 0, stream>>>(Qb, Kb, Vtb, Ao);

  gemm_bt<1><<<dim3(DMODEL / 128, M_PAD / 128), 256, 0, stream>>>(
      Ao, wob, bo, nullptr, nullptr, (float*)d_out, nullptr, nullptr, nullptr);
}